// Round 5
// baseline (168.272 us; speedup 1.0000x reference)
//
#include <hip/hip_runtime.h>

// Problem constants (fixed by the reference):
constexpr int Bn = 8;     // batch
constexpr int En = 8;     // experts
constexpr int Cn = 1024;  // capacity
constexpr int In = 128;   // in features (K)
constexpr int On = 256;   // out features (N)
constexpr int Tn = 8192;  // num tokens
constexpr int ECn = En * Cn;   // 8192 contributions per batch

constexpr int TT  = 64;   // rows per tile (both kernels)
constexpr int CAP = 16;   // contributors per token (Poisson(1); max over 64K ~10)
constexpr int OVF = 32;   // overflow side-list capacity

typedef __fp16 fp16x2 __attribute__((ext_vector_type(2)));
typedef __fp16 f16x8  __attribute__((ext_vector_type(8)));
typedef float  f32x4  __attribute__((ext_vector_type(4)));

__device__ inline unsigned int pk16(float a, float b) {
    fp16x2 h = __builtin_amdgcn_cvt_pkrtz(a, b);   // v_cvt_pkrtz_f16_f32
    return __builtin_bit_cast(unsigned int, h);
}

// ===========================================================================
// PHASE A: dense per-(b,e) GEMM -> y[b][e*C+c][o] f32 (no bias/gate).
//   Block = 64 capacity rows x 256 cols of one (b,e). Coalesced loads,
//   plain stores (no atomics). W converted f32->f16 in-kernel (1 MB, L2-hot).
// ===========================================================================
__global__ __launch_bounds__(256, 2)
void gemm_y(const float* __restrict__ x,     // (B,E,C,I) f32
            const float* __restrict__ w,     // (E,O,I) f32
            float* __restrict__ y)           // (B,E*C,O) f32 ws
{
    __shared__ uint4 Ah[TT * 16];   // 16 KB f16 A tile, frag-swizzled

    const int tid = threadIdx.x;
    const int blk = blockIdx.x;            // (b*8 + e)*16 + ctile
    const int b  = blk >> 7;
    const int e  = (blk >> 4) & 7;
    const int c0 = (blk & 15) * TT;

    const size_t becBase = ((size_t)(b * En + e)) * Cn + c0;
    const float* xrow = x + becBase * In;

    // ---- stage A: 64 consecutive x rows -> f16 frag-swizzled Ah ----
    {
        const int tl = tid >> 2, cq = (tid & 3) * 4;
        const float4* xr = (const float4*)xrow + (size_t)tl * (In / 4);
        #pragma unroll
        for (int it = 0; it < 4; ++it) {
            int cc = cq + it;
            float4 a = xr[2 * cc], b2 = xr[2 * cc + 1];
            uint4 o;
            o.x = pk16(a.x, a.y);   o.y = pk16(a.z, a.w);
            o.z = pk16(b2.x, b2.y); o.w = pk16(b2.z, b2.w);
            Ah[tl * 16 + (cc ^ (tl & 15))] = o;   // verified swizzle
        }
    }

    const int l15  = tid & 15;        // col-in-tile / row-in-tile
    const int q    = (tid >> 4) & 3;  // lane quad
    const int wcol = (tid >> 6) * 64; // wave's 64-column slab

    // ---- B fragments straight from f32 W (replicates verified prep_w) ----
    f16x8 bfr[4][4];
    #pragma unroll
    for (int nt = 0; nt < 4; ++nt)
        #pragma unroll
        for (int s = 0; s < 4; ++s) {
            const int col = wcol + 16 * nt + l15;
            const float4* p = (const float4*)w
                + ((size_t)(e * On + col)) * (In / 4) + (s * 8 + q * 2);
            float4 a = p[0], b2 = p[1];
            uint4 o;
            o.x = pk16(a.x, a.y);   o.y = pk16(a.z, a.w);
            o.z = pk16(b2.x, b2.y); o.w = pk16(b2.z, b2.w);
            bfr[nt][s] = __builtin_bit_cast(f16x8, o);
        }

    __syncthreads();

    // ---- dense MFMA: 64x256 = A(64x128) * W_e^T(128x256) ----
    f32x4 acc[4][4];
    #pragma unroll
    for (int mt = 0; mt < 4; ++mt)
        #pragma unroll
        for (int nt = 0; nt < 4; ++nt) acc[mt][nt] = f32x4{0.f, 0.f, 0.f, 0.f};

    #pragma unroll
    for (int mt = 0; mt < 4; ++mt) {
        const int tl = mt * 16 + l15;
        f16x8 afr[4];
        #pragma unroll
        for (int s = 0; s < 4; ++s)
            afr[s] = __builtin_bit_cast(f16x8, Ah[tl * 16 + ((4 * s + q) ^ (tl & 15))]);
        #pragma unroll
        for (int nt = 0; nt < 4; ++nt)
            #pragma unroll
            for (int s = 0; s < 4; ++s)
                acc[mt][nt] = __builtin_amdgcn_mfma_f32_16x16x32_f16(
                    afr[s], bfr[nt][s], acc[mt][nt], 0, 0, 0);
    }

    // ---- store y (plain stores; C layout: row = q*4+i, col = l15) ----
    float* yb = y + becBase * On;
    #pragma unroll
    for (int mt = 0; mt < 4; ++mt) {
        #pragma unroll
        for (int i = 0; i < 4; ++i) {
            const int tl = mt * 16 + q * 4 + i;
            float* yr = yb + (size_t)tl * On + wcol + l15;
            #pragma unroll
            for (int nt = 0; nt < 4; ++nt)
                yr[16 * nt] = acc[mt][nt][i];
        }
    }
}

// ===========================================================================
// PHASE B: token-owned combine. Block = (b, 64 tokens). Scan batch idx
//   (vectorized, L3-broadcast), build per-token contributor lists in LDS,
//   gather y rows, write each out cell EXACTLY ONCE (no memset, no atomics).
//   out[t] = sum_j y_j * g_j + bias * sum_j g_j   (0 if no contributors)
// ===========================================================================
__global__ __launch_bounds__(256)
void combine(const int*   __restrict__ idx,   // (B,E,C)
             const float* __restrict__ gate,  // (B,E,C)
             const float* __restrict__ y,     // (B,E*C,O) f32 ws
             const float* __restrict__ bias,  // (O)
             float* __restrict__ out)         // (B,T,O)
{
    __shared__ int   lcnt[TT];
    __shared__ float gsum[TT];
    __shared__ unsigned short lslot[TT][CAP];
    __shared__ float lgate[TT][CAP];
    __shared__ int ovfCnt;
    __shared__ unsigned ovfE[OVF];
    __shared__ float    ovfG[OVF];

    const int tid = threadIdx.x;
    const int blk = blockIdx.x;           // b*128 + ttile
    const int b  = blk >> 7;
    const int t0 = (blk & 127) * TT;
    const int*   idxb  = idx  + (size_t)b * ECn;
    const float* gateb = gate + (size_t)b * ECn;

    if (tid < TT) { lcnt[tid] = 0; gsum[tid] = 0.f; }
    if (tid == 0) ovfCnt = 0;
    __syncthreads();

    // ---- vectorized scan over this batch's 8192 indices ----
    {
        const int4* idx4 = (const int4*)idxb;
        #pragma unroll
        for (int s = 0; s < ECn / 1024; ++s) {     // 8 steps of int4
            int i4 = tid + 256 * s;
            int4 tv = idx4[i4];
            int ec0 = i4 * 4;
            #pragma unroll
            for (int k = 0; k < 4; ++k) {
                int t = (k == 0) ? tv.x : (k == 1) ? tv.y : (k == 2) ? tv.z : tv.w;
                unsigned d = (unsigned)(t - t0);
                if (d < (unsigned)TT) {
                    int ec = ec0 + k;
                    float g = gateb[ec];
                    atomicAdd(&gsum[d], g);
                    int pos = atomicAdd(&lcnt[d], 1);
                    if (pos < CAP) {
                        lslot[d][pos] = (unsigned short)ec;
                        lgate[d][pos] = g;
                    } else {
                        int o = atomicAdd(&ovfCnt, 1);
                        if (o < OVF) { ovfE[o] = ((unsigned)d << 16) | (unsigned)ec; ovfG[o] = g; }
                    }
                }
            }
        }
    }
    __syncthreads();

    // ---- gather: 4 threads per token, 64 cols each ----
    const int d = tid >> 2, qt = tid & 3, col0 = qt * 64;
    const float* yb = y + (size_t)b * ECn * On;

    float acc[64];
    #pragma unroll
    for (int k = 0; k < 64; ++k) acc[k] = 0.f;

    const int n = min(lcnt[d], CAP);
    for (int j = 0; j < n; ++j) {
        const int ec = lslot[d][j];
        const float g = lgate[d][j];
        const float4* yr = (const float4*)(yb + (size_t)ec * On + col0);
        #pragma unroll
        for (int k = 0; k < 16; ++k) {
            float4 v = yr[k];
            acc[4 * k + 0] += v.x * g; acc[4 * k + 1] += v.y * g;
            acc[4 * k + 2] += v.z * g; acc[4 * k + 3] += v.w * g;
        }
    }
    // rare overflow entries (normally ovfCnt == 0)
    const int oc = min(ovfCnt, OVF);
    for (int j = 0; j < oc; ++j) {
        if ((int)(ovfE[j] >> 16) == d) {
            const int ec = (int)(ovfE[j] & 0xFFFFu);
            const float g = ovfG[j];
            const float4* yr = (const float4*)(yb + (size_t)ec * On + col0);
            #pragma unroll
            for (int k = 0; k < 16; ++k) {
                float4 v = yr[k];
                acc[4 * k + 0] += v.x * g; acc[4 * k + 1] += v.y * g;
                acc[4 * k + 2] += v.z * g; acc[4 * k + 3] += v.w * g;
            }
        }
    }

    // ---- finish: + bias * gsum, single coalesced store ----
    const float gs = gsum[d];
    float4* orow = (float4*)(out + ((size_t)b * Tn + t0 + d) * On + col0);
    const float4* bp = (const float4*)(bias + col0);
    #pragma unroll
    for (int k = 0; k < 16; ++k) {
        float4 bb = bp[k];
        float4 r;
        r.x = acc[4 * k + 0] + bb.x * gs; r.y = acc[4 * k + 1] + bb.y * gs;
        r.z = acc[4 * k + 2] + bb.z * gs; r.w = acc[4 * k + 3] + bb.w * gs;
        orow[k] = r;
    }
}

// ===========================================================================
// FALLBACK (ws too small): proven round-3 path — prep_w + memset + atomic
// scatter GEMM.
// ===========================================================================
__global__ void prep_w(const float4* __restrict__ w4, uint4* __restrict__ wh4) {
    int f = blockIdx.x * 256 + threadIdx.x;  // < E*4*4*256 = 32768
    int col = f & 255, q = (f >> 8) & 3, s = (f >> 10) & 3, e = f >> 12;
    const float4* p = w4 + ((size_t)(e * On + col)) * (In / 4) + (s * 8 + q * 2);
    float4 a = p[0], b = p[1];
    uint4 o;
    o.x = pk16(a.x, a.y); o.y = pk16(a.z, a.w);
    o.z = pk16(b.x, b.y); o.w = pk16(b.z, b.w);
    wh4[f] = o;
}

__global__ __launch_bounds__(256, 2)
void gemm_scatter(const float* __restrict__ x, const int* __restrict__ idx,
                  const float* __restrict__ gate, const uint4* __restrict__ wh4,
                  const float* __restrict__ bias, float* __restrict__ out)
{
    __shared__ uint4 Ah[TT * 16];
    __shared__ int   sIdx[TT];
    __shared__ float sG[TT];

    const int tid = threadIdx.x;
    const int blk = blockIdx.x;
    const int b  = blk >> 7;
    const int e  = (blk >> 4) & 7;
    const int c0 = (blk & 15) * TT;

    const size_t becBase = ((size_t)(b * En + e)) * Cn + c0;
    const float* xrow = x + becBase * In;

    if (tid < TT) {
        sIdx[tid] = idx[becBase + tid];
        sG[tid]   = gate[becBase + tid];
    }
    {
        const int tl = tid >> 2, cq = (tid & 3) * 4;
        const float4* xr = (const float4*)xrow + (size_t)tl * (In / 4);
        #pragma unroll
        for (int it = 0; it < 4; ++it) {
            int cc = cq + it;
            float4 a = xr[2 * cc], b2 = xr[2 * cc + 1];
            uint4 o;
            o.x = pk16(a.x, a.y);   o.y = pk16(a.z, a.w);
            o.z = pk16(b2.x, b2.y); o.w = pk16(b2.z, b2.w);
            Ah[tl * 16 + (cc ^ (tl & 15))] = o;
        }
    }
    const int l15  = tid & 15;
    const int q    = (tid >> 4) & 3;
    const int wcol = (tid >> 6) * 64;

    f16x8 bfr[4][4];
    #pragma unroll
    for (int nt = 0; nt < 4; ++nt)
        #pragma unroll
        for (int s = 0; s < 4; ++s)
            bfr[nt][s] = __builtin_bit_cast(f16x8,
                wh4[(size_t)((e * 4 + s) * 4 + q) * 256 + wcol + 16 * nt + l15]);

    __syncthreads();

    f32x4 acc[4][4];
    #pragma unroll
    for (int mt = 0; mt < 4; ++mt)
        #pragma unroll
        for (int nt = 0; nt < 4; ++nt) acc[mt][nt] = f32x4{0.f, 0.f, 0.f, 0.f};

    #pragma unroll
    for (int mt = 0; mt < 4; ++mt) {
        const int tl = mt * 16 + l15;
        f16x8 afr[4];
        #pragma unroll
        for (int s = 0; s < 4; ++s)
            afr[s] = __builtin_bit_cast(f16x8, Ah[tl * 16 + ((4 * s + q) ^ (tl & 15))]);
        #pragma unroll
        for (int nt = 0; nt < 4; ++nt)
            #pragma unroll
            for (int s = 0; s < 4; ++s)
                acc[mt][nt] = __builtin_amdgcn_mfma_f32_16x16x32_f16(
                    afr[s], bfr[nt][s], acc[mt][nt], 0, 0, 0);
    }

    float bv[4];
    #pragma unroll
    for (int nt = 0; nt < 4; ++nt) bv[nt] = bias[wcol + 16 * nt + l15];

    float* ob = out + (size_t)b * Tn * On;
    #pragma unroll
    for (int mt = 0; mt < 4; ++mt) {
        #pragma unroll
        for (int i = 0; i < 4; ++i) {
            const int tl = mt * 16 + q * 4 + i;
            const int t  = sIdx[tl];
            const float g = sG[tl];
            float* orow = ob + (size_t)t * On + wcol + l15;
            #pragma unroll
            for (int nt = 0; nt < 4; ++nt)
                atomicAdd(&orow[16 * nt], (acc[mt][nt][i] + bv[nt]) * g);
        }
    }
}

extern "C" void kernel_launch(void* const* d_in, const int* in_sizes, int n_in,
                              void* d_out, int out_size, void* d_ws, size_t ws_size,
                              hipStream_t stream) {
    const float* x    = (const float*)d_in[0];  // (B,E,C,I) fp32
    const int*   idx  = (const int*)  d_in[1];  // (B,E,C) int32
    const float* gate = (const float*)d_in[2];  // (B,E,C) fp32
    const float* w    = (const float*)d_in[3];  // (E,O,I) fp32
    const float* bias = (const float*)d_in[4];  // (O,) fp32
    float* out = (float*)d_out;

    const size_t needY = (size_t)Bn * ECn * On * sizeof(float);  // 67.1 MB

    if (ws_size >= needY) {
        // two-phase: dense GEMM -> y ws, then token-owned gather-combine
        float* yws = (float*)d_ws;
        gemm_y <<<Bn * En * (Cn / TT), 256, 0, stream>>>(x, w, yws);
        combine<<<Bn * (Tn / TT),      256, 0, stream>>>(idx, gate, yws, bias, out);
    } else {
        // fallback: proven atomic-scatter path (round 3)
        uint4* wh4 = (uint4*)d_ws;  // 512 KB packed f16 weights
        prep_w<<<(En * 4 * 4 * On) / 256, 256, 0, stream>>>((const float4*)w, wh4);
        hipMemsetAsync(d_out, 0, (size_t)out_size, stream);
        gemm_scatter<<<Bn * En * (Cn / TT), 256, 0, stream>>>(x, idx, gate, wh4, bias, out);
    }
}

// Round 6
// 140.709 us; speedup vs baseline: 1.1959x; 1.1959x over previous
//
#include <hip/hip_runtime.h>

// Problem constants (fixed by the reference):
constexpr int Bn = 8;     // batch
constexpr int En = 8;     // experts
constexpr int Cn = 1024;  // capacity
constexpr int In = 128;   // in features (K)
constexpr int On = 256;   // out features (N)
constexpr int Tn = 8192;  // num tokens
constexpr int ECn = En * Cn;   // 8192 contributions per batch

constexpr int TT  = 64;   // rows per tile (both kernels)
constexpr int CAP = 16;   // contributors per token (Poisson(1); max over 64K ~10)
constexpr int OVF = 32;   // overflow side-list capacity

typedef __fp16 fp16x2 __attribute__((ext_vector_type(2)));
typedef __fp16 f16x8  __attribute__((ext_vector_type(8)));
typedef float  f32x4  __attribute__((ext_vector_type(4)));

__device__ inline unsigned int pk16(float a, float b) {
    fp16x2 h = __builtin_amdgcn_cvt_pkrtz(a, b);   // v_cvt_pkrtz_f16_f32
    return __builtin_bit_cast(unsigned int, h);
}

// ===========================================================================
// PHASE A: dense per-(b,e) GEMM -> y[b][e*C+c][o] f32 (no bias/gate).
//   Block = 64 capacity rows x 256 cols of one (b,e). Coalesced loads,
//   plain stores (no atomics). W converted f32->f16 in-kernel (1 MB, L2-hot).
//   (unchanged from round 5 — proven)
// ===========================================================================
__global__ __launch_bounds__(256, 2)
void gemm_y(const float* __restrict__ x,     // (B,E,C,I) f32
            const float* __restrict__ w,     // (E,O,I) f32
            float* __restrict__ y)           // (B,E*C,O) f32 ws
{
    __shared__ uint4 Ah[TT * 16];   // 16 KB f16 A tile, frag-swizzled

    const int tid = threadIdx.x;
    const int blk = blockIdx.x;            // (b*8 + e)*16 + ctile
    const int b  = blk >> 7;
    const int e  = (blk >> 4) & 7;
    const int c0 = (blk & 15) * TT;

    const size_t becBase = ((size_t)(b * En + e)) * Cn + c0;
    const float* xrow = x + becBase * In;

    // ---- stage A: 64 consecutive x rows -> f16 frag-swizzled Ah ----
    {
        const int tl = tid >> 2, cq = (tid & 3) * 4;
        const float4* xr = (const float4*)xrow + (size_t)tl * (In / 4);
        #pragma unroll
        for (int it = 0; it < 4; ++it) {
            int cc = cq + it;
            float4 a = xr[2 * cc], b2 = xr[2 * cc + 1];
            uint4 o;
            o.x = pk16(a.x, a.y);   o.y = pk16(a.z, a.w);
            o.z = pk16(b2.x, b2.y); o.w = pk16(b2.z, b2.w);
            Ah[tl * 16 + (cc ^ (tl & 15))] = o;   // verified swizzle
        }
    }

    const int l15  = tid & 15;        // col-in-tile / row-in-tile
    const int q    = (tid >> 4) & 3;  // lane quad
    const int wcol = (tid >> 6) * 64; // wave's 64-column slab

    // ---- B fragments straight from f32 W (replicates verified prep_w) ----
    f16x8 bfr[4][4];
    #pragma unroll
    for (int nt = 0; nt < 4; ++nt)
        #pragma unroll
        for (int s = 0; s < 4; ++s) {
            const int col = wcol + 16 * nt + l15;
            const float4* p = (const float4*)w
                + ((size_t)(e * On + col)) * (In / 4) + (s * 8 + q * 2);
            float4 a = p[0], b2 = p[1];
            uint4 o;
            o.x = pk16(a.x, a.y);   o.y = pk16(a.z, a.w);
            o.z = pk16(b2.x, b2.y); o.w = pk16(b2.z, b2.w);
            bfr[nt][s] = __builtin_bit_cast(f16x8, o);
        }

    __syncthreads();

    // ---- dense MFMA: 64x256 = A(64x128) * W_e^T(128x256) ----
    f32x4 acc[4][4];
    #pragma unroll
    for (int mt = 0; mt < 4; ++mt)
        #pragma unroll
        for (int nt = 0; nt < 4; ++nt) acc[mt][nt] = f32x4{0.f, 0.f, 0.f, 0.f};

    #pragma unroll
    for (int mt = 0; mt < 4; ++mt) {
        const int tl = mt * 16 + l15;
        f16x8 afr[4];
        #pragma unroll
        for (int s = 0; s < 4; ++s)
            afr[s] = __builtin_bit_cast(f16x8, Ah[tl * 16 + ((4 * s + q) ^ (tl & 15))]);
        #pragma unroll
        for (int nt = 0; nt < 4; ++nt)
            #pragma unroll
            for (int s = 0; s < 4; ++s)
                acc[mt][nt] = __builtin_amdgcn_mfma_f32_16x16x32_f16(
                    afr[s], bfr[nt][s], acc[mt][nt], 0, 0, 0);
    }

    // ---- store y (plain stores; C layout: row = q*4+i, col = l15) ----
    float* yb = y + becBase * On;
    #pragma unroll
    for (int mt = 0; mt < 4; ++mt) {
        #pragma unroll
        for (int i = 0; i < 4; ++i) {
            const int tl = mt * 16 + q * 4 + i;
            float* yr = yb + (size_t)tl * On + wcol + l15;
            #pragma unroll
            for (int nt = 0; nt < 4; ++nt)
                yr[16 * nt] = acc[mt][nt][i];
        }
    }
}

// ===========================================================================
// PHASE B: token-owned combine, WAVE-PER-ROW gather.
//   Block = (b, 64 tokens); wave wv owns tokens wv*16..wv*16+15 (static
//   unroll -> acc stays in VGPRs). Per contributor the WHOLE wave loads the
//   1 KB y row as 64 x float4 (fully coalesced, wave-uniform loop, no
//   divergence). First contributors of all 16 tokens issued as one burst
//   (16 outstanding loads). Out/bias accesses lane-contiguous.
// ===========================================================================
__global__ __launch_bounds__(256)
void combine(const int*   __restrict__ idx,   // (B,E,C)
             const float* __restrict__ gate,  // (B,E,C)
             const float* __restrict__ y,     // (B,E*C,O) f32 ws
             const float* __restrict__ bias,  // (O)
             float* __restrict__ out)         // (B,T,O)
{
    __shared__ int   lcnt[TT];
    __shared__ float gsum[TT];
    __shared__ unsigned short lslot[TT][CAP];
    __shared__ float lgate[TT][CAP];
    __shared__ int ovfCnt;
    __shared__ unsigned ovfE[OVF];
    __shared__ float    ovfG[OVF];

    const int tid = threadIdx.x;
    const int blk = blockIdx.x;           // b*128 + ttile
    const int b  = blk >> 7;
    const int t0 = (blk & 127) * TT;
    const int*   idxb  = idx  + (size_t)b * ECn;
    const float* gateb = gate + (size_t)b * ECn;

    if (tid < TT) { lcnt[tid] = 0; gsum[tid] = 0.f; }
    if (tid == 0) ovfCnt = 0;
    __syncthreads();

    // ---- vectorized scan over this batch's 8192 indices ----
    {
        const int4* idx4 = (const int4*)idxb;
        #pragma unroll
        for (int s = 0; s < ECn / 1024; ++s) {     // 8 steps of int4
            int i4 = tid + 256 * s;
            int4 tv = idx4[i4];
            int ec0 = i4 * 4;
            #pragma unroll
            for (int k = 0; k < 4; ++k) {
                int t = (k == 0) ? tv.x : (k == 1) ? tv.y : (k == 2) ? tv.z : tv.w;
                unsigned d = (unsigned)(t - t0);
                if (d < (unsigned)TT) {
                    int ec = ec0 + k;
                    float g = gateb[ec];
                    atomicAdd(&gsum[d], g);
                    int pos = atomicAdd(&lcnt[d], 1);
                    if (pos < CAP) {
                        lslot[d][pos] = (unsigned short)ec;
                        lgate[d][pos] = g;
                    } else {
                        int o = atomicAdd(&ovfCnt, 1);
                        if (o < OVF) { ovfE[o] = ((unsigned)d << 16) | (unsigned)ec; ovfG[o] = g; }
                    }
                }
            }
        }
    }
    __syncthreads();

    const int wv = tid >> 6;         // wave id 0..3
    const int l  = tid & 63;         // lane: covers cols 4l..4l+3
    const int d0 = wv * 16;          // first token owned by this wave
    const float* yb = y + (size_t)b * ECn * On;

    f32x4 acc[16];
    int   n[16];

    // ---- burst: first contributor row of each of the 16 tokens ----
    #pragma unroll
    for (int tk = 0; tk < 16; ++tk) {
        n[tk] = min(lcnt[d0 + tk], CAP);
        acc[tk] = f32x4{0.f, 0.f, 0.f, 0.f};
        if (n[tk] > 0) {
            const int ec = lslot[d0 + tk][0];
            acc[tk] = ((const f32x4*)(yb + (size_t)ec * On))[l];
        }
    }
    #pragma unroll
    for (int tk = 0; tk < 16; ++tk)
        if (n[tk] > 0) acc[tk] *= lgate[d0 + tk][0];

    // ---- remaining contributors (wave-uniform loops; P(n>=2) ~ 26%) ----
    #pragma unroll
    for (int tk = 0; tk < 16; ++tk) {
        for (int j = 1; j < n[tk]; ++j) {
            const int ec = lslot[d0 + tk][j];
            const float g = lgate[d0 + tk][j];
            f32x4 v = ((const f32x4*)(yb + (size_t)ec * On))[l];
            acc[tk] += v * g;
        }
    }

    // ---- rare overflow entries (normally ovfCnt == 0) ----
    const int oc = min(ovfCnt, OVF);
    for (int j = 0; j < oc; ++j) {
        const int dd = (int)(ovfE[j] >> 16);
        const int tk = dd - d0;
        if ((unsigned)tk < 16u) {
            const int ec = (int)(ovfE[j] & 0xFFFFu);
            const float g = ovfG[j];
            f32x4 v = ((const f32x4*)(yb + (size_t)ec * On))[l];
            #pragma unroll
            for (int k = 0; k < 16; ++k)
                if (tk == k) acc[k] += v * g;   // static acc index
        }
    }

    // ---- epilogue: + bias*gsum, one coalesced 1 KB store per token ----
    const f32x4 bv = ((const f32x4*)bias)[l];
    #pragma unroll
    for (int tk = 0; tk < 16; ++tk) {
        const int d = d0 + tk;
        const float gs = gsum[d];
        f32x4 r = acc[tk] + bv * gs;
        ((f32x4*)(out + ((size_t)b * Tn + t0 + d) * On))[l] = r;
    }
}

// ===========================================================================
// FALLBACK (ws too small): proven round-3 path — prep_w + memset + atomic
// scatter GEMM.
// ===========================================================================
__global__ void prep_w(const float4* __restrict__ w4, uint4* __restrict__ wh4) {
    int f = blockIdx.x * 256 + threadIdx.x;  // < E*4*4*256 = 32768
    int col = f & 255, q = (f >> 8) & 3, s = (f >> 10) & 3, e = f >> 12;
    const float4* p = w4 + ((size_t)(e * On + col)) * (In / 4) + (s * 8 + q * 2);
    float4 a = p[0], b = p[1];
    uint4 o;
    o.x = pk16(a.x, a.y); o.y = pk16(a.z, a.w);
    o.z = pk16(b.x, b.y); o.w = pk16(b.z, b.w);
    wh4[f] = o;
}

__global__ __launch_bounds__(256, 2)
void gemm_scatter(const float* __restrict__ x, const int* __restrict__ idx,
                  const float* __restrict__ gate, const uint4* __restrict__ wh4,
                  const float* __restrict__ bias, float* __restrict__ out)
{
    __shared__ uint4 Ah[TT * 16];
    __shared__ int   sIdx[TT];
    __shared__ float sG[TT];

    const int tid = threadIdx.x;
    const int blk = blockIdx.x;
    const int b  = blk >> 7;
    const int e  = (blk >> 4) & 7;
    const int c0 = (blk & 15) * TT;

    const size_t becBase = ((size_t)(b * En + e)) * Cn + c0;
    const float* xrow = x + becBase * In;

    if (tid < TT) {
        sIdx[tid] = idx[becBase + tid];
        sG[tid]   = gate[becBase + tid];
    }
    {
        const int tl = tid >> 2, cq = (tid & 3) * 4;
        const float4* xr = (const float4*)xrow + (size_t)tl * (In / 4);
        #pragma unroll
        for (int it = 0; it < 4; ++it) {
            int cc = cq + it;
            float4 a = xr[2 * cc], b2 = xr[2 * cc + 1];
            uint4 o;
            o.x = pk16(a.x, a.y);   o.y = pk16(a.z, a.w);
            o.z = pk16(b2.x, b2.y); o.w = pk16(b2.z, b2.w);
            Ah[tl * 16 + (cc ^ (tl & 15))] = o;
        }
    }
    const int l15  = tid & 15;
    const int q    = (tid >> 4) & 3;
    const int wcol = (tid >> 6) * 64;

    f16x8 bfr[4][4];
    #pragma unroll
    for (int nt = 0; nt < 4; ++nt)
        #pragma unroll
        for (int s = 0; s < 4; ++s)
            bfr[nt][s] = __builtin_bit_cast(f16x8,
                wh4[(size_t)((e * 4 + s) * 4 + q) * 256 + wcol + 16 * nt + l15]);

    __syncthreads();

    f32x4 acc[4][4];
    #pragma unroll
    for (int mt = 0; mt < 4; ++mt)
        #pragma unroll
        for (int nt = 0; nt < 4; ++nt) acc[mt][nt] = f32x4{0.f, 0.f, 0.f, 0.f};

    #pragma unroll
    for (int mt = 0; mt < 4; ++mt) {
        const int tl = mt * 16 + l15;
        f16x8 afr[4];
        #pragma unroll
        for (int s = 0; s < 4; ++s)
            afr[s] = __builtin_bit_cast(f16x8, Ah[tl * 16 + ((4 * s + q) ^ (tl & 15))]);
        #pragma unroll
        for (int nt = 0; nt < 4; ++nt)
            #pragma unroll
            for (int s = 0; s < 4; ++s)
                acc[mt][nt] = __builtin_amdgcn_mfma_f32_16x16x32_f16(
                    afr[s], bfr[nt][s], acc[mt][nt], 0, 0, 0);
    }

    float bv[4];
    #pragma unroll
    for (int nt = 0; nt < 4; ++nt) bv[nt] = bias[wcol + 16 * nt + l15];

    float* ob = out + (size_t)b * Tn * On;
    #pragma unroll
    for (int mt = 0; mt < 4; ++mt) {
        #pragma unroll
        for (int i = 0; i < 4; ++i) {
            const int tl = mt * 16 + q * 4 + i;
            const int t  = sIdx[tl];
            const float g = sG[tl];
            float* orow = ob + (size_t)t * On + wcol + l15;
            #pragma unroll
            for (int nt = 0; nt < 4; ++nt)
                atomicAdd(&orow[16 * nt], (acc[mt][nt][i] + bv[nt]) * g);
        }
    }
}

extern "C" void kernel_launch(void* const* d_in, const int* in_sizes, int n_in,
                              void* d_out, int out_size, void* d_ws, size_t ws_size,
                              hipStream_t stream) {
    const float* x    = (const float*)d_in[0];  // (B,E,C,I) fp32
    const int*   idx  = (const int*)  d_in[1];  // (B,E,C) int32
    const float* gate = (const float*)d_in[2];  // (B,E,C) fp32
    const float* w    = (const float*)d_in[3];  // (E,O,I) fp32
    const float* bias = (const float*)d_in[4];  // (O,) fp32
    float* out = (float*)d_out;

    const size_t needY = (size_t)Bn * ECn * On * sizeof(float);  // 67.1 MB

    if (ws_size >= needY) {
        // two-phase: dense GEMM -> y ws, then token-owned gather-combine
        float* yws = (float*)d_ws;
        gemm_y <<<Bn * En * (Cn / TT), 256, 0, stream>>>(x, w, yws);
        combine<<<Bn * (Tn / TT),      256, 0, stream>>>(idx, gate, yws, bias, out);
    } else {
        // fallback: proven atomic-scatter path (round 3)
        uint4* wh4 = (uint4*)d_ws;  // 512 KB packed f16 weights
        prep_w<<<(En * 4 * 4 * On) / 256, 256, 0, stream>>>((const float4*)w, wh4);
        hipMemsetAsync(d_out, 0, (size_t)out_size, stream);
        gemm_scatter<<<Bn * En * (Cn / TT), 256, 0, stream>>>(x, idx, gate, wh4, bias, out);
    }
}

// Round 7
// 137.132 us; speedup vs baseline: 1.2271x; 1.0261x over previous
//
#include <hip/hip_runtime.h>

// Problem constants (fixed by the reference):
constexpr int Bn = 8;     // batch
constexpr int En = 8;     // experts
constexpr int Cn = 1024;  // capacity
constexpr int In = 128;   // in features (K)
constexpr int On = 256;   // out features (N)
constexpr int Tn = 8192;  // num tokens
constexpr int ECn = En * Cn;   // 8192 contributions per batch

constexpr int TT  = 64;   // rows per tile (both kernels)
constexpr int CAP = 16;   // contributors per token (Poisson(1); max over 64K ~10)
constexpr int OVF = 32;   // overflow side-list capacity

typedef __fp16 fp16x2 __attribute__((ext_vector_type(2)));
typedef __fp16 f16x8  __attribute__((ext_vector_type(8)));
typedef float  f32x4  __attribute__((ext_vector_type(4)));

__device__ inline unsigned int pk16(float a, float b) {
    fp16x2 h = __builtin_amdgcn_cvt_pkrtz(a, b);   // v_cvt_pkrtz_f16_f32
    return __builtin_bit_cast(unsigned int, h);
}

// ===========================================================================
// PHASE A: dense per-(b,e) GEMM -> y[b][e*C+c][o] f32 (no bias/gate).
//   Block = 64 capacity rows x 256 cols of one (b,e). Coalesced loads,
//   plain stores (no atomics). W converted f32->f16 in-kernel (1 MB, L2-hot).
//   launch_bounds(256,3): reg footprint ~136 (72 VGPR + 64 acc) fits
//   3 waves/SIMD (512/136=3.7) -> 3 blocks/CU instead of 2.
// ===========================================================================
__global__ __launch_bounds__(256, 3)
void gemm_y(const float* __restrict__ x,     // (B,E,C,I) f32
            const float* __restrict__ w,     // (E,O,I) f32
            float* __restrict__ y)           // (B,E*C,O) f32 ws
{
    __shared__ uint4 Ah[TT * 16];   // 16 KB f16 A tile, frag-swizzled

    const int tid = threadIdx.x;
    const int blk = blockIdx.x;            // (b*8 + e)*16 + ctile
    const int b  = blk >> 7;
    const int e  = (blk >> 4) & 7;
    const int c0 = (blk & 15) * TT;

    const size_t becBase = ((size_t)(b * En + e)) * Cn + c0;
    const float* xrow = x + becBase * In;

    // ---- stage A: 64 consecutive x rows -> f16 frag-swizzled Ah ----
    {
        const int tl = tid >> 2, cq = (tid & 3) * 4;
        const float4* xr = (const float4*)xrow + (size_t)tl * (In / 4);
        #pragma unroll
        for (int it = 0; it < 4; ++it) {
            int cc = cq + it;
            float4 a = xr[2 * cc], b2 = xr[2 * cc + 1];
            uint4 o;
            o.x = pk16(a.x, a.y);   o.y = pk16(a.z, a.w);
            o.z = pk16(b2.x, b2.y); o.w = pk16(b2.z, b2.w);
            Ah[tl * 16 + (cc ^ (tl & 15))] = o;   // verified swizzle
        }
    }

    const int l15  = tid & 15;        // col-in-tile / row-in-tile
    const int q    = (tid >> 4) & 3;  // lane quad
    const int wcol = (tid >> 6) * 64; // wave's 64-column slab

    // ---- B fragments straight from f32 W (replicates verified prep_w) ----
    f16x8 bfr[4][4];
    #pragma unroll
    for (int nt = 0; nt < 4; ++nt)
        #pragma unroll
        for (int s = 0; s < 4; ++s) {
            const int col = wcol + 16 * nt + l15;
            const float4* p = (const float4*)w
                + ((size_t)(e * On + col)) * (In / 4) + (s * 8 + q * 2);
            float4 a = p[0], b2 = p[1];
            uint4 o;
            o.x = pk16(a.x, a.y);   o.y = pk16(a.z, a.w);
            o.z = pk16(b2.x, b2.y); o.w = pk16(b2.z, b2.w);
            bfr[nt][s] = __builtin_bit_cast(f16x8, o);
        }

    __syncthreads();

    // ---- dense MFMA: 64x256 = A(64x128) * W_e^T(128x256) ----
    f32x4 acc[4][4];
    #pragma unroll
    for (int mt = 0; mt < 4; ++mt)
        #pragma unroll
        for (int nt = 0; nt < 4; ++nt) acc[mt][nt] = f32x4{0.f, 0.f, 0.f, 0.f};

    #pragma unroll
    for (int mt = 0; mt < 4; ++mt) {
        const int tl = mt * 16 + l15;
        f16x8 afr[4];
        #pragma unroll
        for (int s = 0; s < 4; ++s)
            afr[s] = __builtin_bit_cast(f16x8, Ah[tl * 16 + ((4 * s + q) ^ (tl & 15))]);
        #pragma unroll
        for (int nt = 0; nt < 4; ++nt)
            #pragma unroll
            for (int s = 0; s < 4; ++s)
                acc[mt][nt] = __builtin_amdgcn_mfma_f32_16x16x32_f16(
                    afr[s], bfr[nt][s], acc[mt][nt], 0, 0, 0);
    }

    // ---- store y (plain stores; C layout: row = q*4+i, col = l15) ----
    float* yb = y + becBase * On;
    #pragma unroll
    for (int mt = 0; mt < 4; ++mt) {
        #pragma unroll
        for (int i = 0; i < 4; ++i) {
            const int tl = mt * 16 + q * 4 + i;
            float* yr = yb + (size_t)tl * On + wcol + l15;
            #pragma unroll
            for (int nt = 0; nt < 4; ++nt)
                yr[16 * nt] = acc[mt][nt][i];
        }
    }
}

// ===========================================================================
// PHASE B: token-owned combine, WAVE-PER-ROW gather (proven round 6).
//   launch_bounds(256,4): VGPR ~68+acc fits 128-cap -> 4 blocks/CU
//   guaranteed (grid 1024 fully co-resident).
//   Scan now vector-loads gate as float4 in lockstep with the int4 idx
//   load (removes the dependent scattered gate load per hit).
// ===========================================================================
__global__ __launch_bounds__(256, 4)
void combine(const int*   __restrict__ idx,   // (B,E,C)
             const float* __restrict__ gate,  // (B,E,C)
             const float* __restrict__ y,     // (B,E*C,O) f32 ws
             const float* __restrict__ bias,  // (O)
             float* __restrict__ out)         // (B,T,O)
{
    __shared__ int   lcnt[TT];
    __shared__ float gsum[TT];
    __shared__ unsigned short lslot[TT][CAP];
    __shared__ float lgate[TT][CAP];
    __shared__ int ovfCnt;
    __shared__ unsigned ovfE[OVF];
    __shared__ float    ovfG[OVF];

    const int tid = threadIdx.x;
    const int blk = blockIdx.x;           // b*128 + ttile
    const int b  = blk >> 7;
    const int t0 = (blk & 127) * TT;
    const int*   idxb  = idx  + (size_t)b * ECn;
    const float* gateb = gate + (size_t)b * ECn;

    if (tid < TT) { lcnt[tid] = 0; gsum[tid] = 0.f; }
    if (tid == 0) ovfCnt = 0;
    __syncthreads();

    // ---- vectorized scan over this batch's 8192 indices (idx4 + gate4) ----
    {
        const int4*   idx4  = (const int4*)idxb;
        const float4* gate4 = (const float4*)gateb;
        #pragma unroll
        for (int s = 0; s < ECn / 1024; ++s) {     // 8 steps of int4
            int i4 = tid + 256 * s;
            int4   tv = idx4[i4];
            float4 gv = gate4[i4];
            int ec0 = i4 * 4;
            #pragma unroll
            for (int k = 0; k < 4; ++k) {
                int   t = (k == 0) ? tv.x : (k == 1) ? tv.y : (k == 2) ? tv.z : tv.w;
                float g = (k == 0) ? gv.x : (k == 1) ? gv.y : (k == 2) ? gv.z : gv.w;
                unsigned d = (unsigned)(t - t0);
                if (d < (unsigned)TT) {
                    int ec = ec0 + k;
                    atomicAdd(&gsum[d], g);
                    int pos = atomicAdd(&lcnt[d], 1);
                    if (pos < CAP) {
                        lslot[d][pos] = (unsigned short)ec;
                        lgate[d][pos] = g;
                    } else {
                        int o = atomicAdd(&ovfCnt, 1);
                        if (o < OVF) { ovfE[o] = ((unsigned)d << 16) | (unsigned)ec; ovfG[o] = g; }
                    }
                }
            }
        }
    }
    __syncthreads();

    const int wv = tid >> 6;         // wave id 0..3
    const int l  = tid & 63;         // lane: covers cols 4l..4l+3
    const int d0 = wv * 16;          // first token owned by this wave
    const float* yb = y + (size_t)b * ECn * On;

    f32x4 acc[16];
    int   n[16];

    // ---- burst: first contributor row of each of the 16 tokens ----
    #pragma unroll
    for (int tk = 0; tk < 16; ++tk) {
        n[tk] = min(lcnt[d0 + tk], CAP);
        acc[tk] = f32x4{0.f, 0.f, 0.f, 0.f};
        if (n[tk] > 0) {
            const int ec = lslot[d0 + tk][0];
            acc[tk] = ((const f32x4*)(yb + (size_t)ec * On))[l];
        }
    }
    #pragma unroll
    for (int tk = 0; tk < 16; ++tk)
        if (n[tk] > 0) acc[tk] *= lgate[d0 + tk][0];

    // ---- remaining contributors (wave-uniform loops; P(n>=2) ~ 26%) ----
    #pragma unroll
    for (int tk = 0; tk < 16; ++tk) {
        for (int j = 1; j < n[tk]; ++j) {
            const int ec = lslot[d0 + tk][j];
            const float g = lgate[d0 + tk][j];
            f32x4 v = ((const f32x4*)(yb + (size_t)ec * On))[l];
            acc[tk] += v * g;
        }
    }

    // ---- rare overflow entries (normally ovfCnt == 0) ----
    const int oc = min(ovfCnt, OVF);
    for (int j = 0; j < oc; ++j) {
        const int dd = (int)(ovfE[j] >> 16);
        const int tk = dd - d0;
        if ((unsigned)tk < 16u) {
            const int ec = (int)(ovfE[j] & 0xFFFFu);
            const float g = ovfG[j];
            f32x4 v = ((const f32x4*)(yb + (size_t)ec * On))[l];
            #pragma unroll
            for (int k = 0; k < 16; ++k)
                if (tk == k) acc[k] += v * g;   // static acc index
        }
    }

    // ---- epilogue: + bias*gsum, one coalesced 1 KB store per token ----
    const f32x4 bv = ((const f32x4*)bias)[l];
    #pragma unroll
    for (int tk = 0; tk < 16; ++tk) {
        const int d = d0 + tk;
        const float gs = gsum[d];
        f32x4 r = acc[tk] + bv * gs;
        ((f32x4*)(out + ((size_t)b * Tn + t0 + d) * On))[l] = r;
    }
}

// ===========================================================================
// FALLBACK (ws too small): proven round-3 path — prep_w + memset + atomic
// scatter GEMM.
// ===========================================================================
__global__ void prep_w(const float4* __restrict__ w4, uint4* __restrict__ wh4) {
    int f = blockIdx.x * 256 + threadIdx.x;  // < E*4*4*256 = 32768
    int col = f & 255, q = (f >> 8) & 3, s = (f >> 10) & 3, e = f >> 12;
    const float4* p = w4 + ((size_t)(e * On + col)) * (In / 4) + (s * 8 + q * 2);
    float4 a = p[0], b = p[1];
    uint4 o;
    o.x = pk16(a.x, a.y); o.y = pk16(a.z, a.w);
    o.z = pk16(b.x, b.y); o.w = pk16(b.z, b.w);
    wh4[f] = o;
}

__global__ __launch_bounds__(256, 2)
void gemm_scatter(const float* __restrict__ x, const int* __restrict__ idx,
                  const float* __restrict__ gate, const uint4* __restrict__ wh4,
                  const float* __restrict__ bias, float* __restrict__ out)
{
    __shared__ uint4 Ah[TT * 16];
    __shared__ int   sIdx[TT];
    __shared__ float sG[TT];

    const int tid = threadIdx.x;
    const int blk = blockIdx.x;
    const int b  = blk >> 7;
    const int e  = (blk >> 4) & 7;
    const int c0 = (blk & 15) * TT;

    const size_t becBase = ((size_t)(b * En + e)) * Cn + c0;
    const float* xrow = x + becBase * In;

    if (tid < TT) {
        sIdx[tid] = idx[becBase + tid];
        sG[tid]   = gate[becBase + tid];
    }
    {
        const int tl = tid >> 2, cq = (tid & 3) * 4;
        const float4* xr = (const float4*)xrow + (size_t)tl * (In / 4);
        #pragma unroll
        for (int it = 0; it < 4; ++it) {
            int cc = cq + it;
            float4 a = xr[2 * cc], b2 = xr[2 * cc + 1];
            uint4 o;
            o.x = pk16(a.x, a.y);   o.y = pk16(a.z, a.w);
            o.z = pk16(b2.x, b2.y); o.w = pk16(b2.z, b2.w);
            Ah[tl * 16 + (cc ^ (tl & 15))] = o;
        }
    }
    const int l15  = tid & 15;
    const int q    = (tid >> 4) & 3;
    const int wcol = (tid >> 6) * 64;

    f16x8 bfr[4][4];
    #pragma unroll
    for (int nt = 0; nt < 4; ++nt)
        #pragma unroll
        for (int s = 0; s < 4; ++s)
            bfr[nt][s] = __builtin_bit_cast(f16x8,
                wh4[(size_t)((e * 4 + s) * 4 + q) * 256 + wcol + 16 * nt + l15]);

    __syncthreads();

    f32x4 acc[4][4];
    #pragma unroll
    for (int mt = 0; mt < 4; ++mt)
        #pragma unroll
        for (int nt = 0; nt < 4; ++nt) acc[mt][nt] = f32x4{0.f, 0.f, 0.f, 0.f};

    #pragma unroll
    for (int mt = 0; mt < 4; ++mt) {
        const int tl = mt * 16 + l15;
        f16x8 afr[4];
        #pragma unroll
        for (int s = 0; s < 4; ++s)
            afr[s] = __builtin_bit_cast(f16x8, Ah[tl * 16 + ((4 * s + q) ^ (tl & 15))]);
        #pragma unroll
        for (int nt = 0; nt < 4; ++nt)
            #pragma unroll
            for (int s = 0; s < 4; ++s)
                acc[mt][nt] = __builtin_amdgcn_mfma_f32_16x16x32_f16(
                    afr[s], bfr[nt][s], acc[mt][nt], 0, 0, 0);
    }

    float bv[4];
    #pragma unroll
    for (int nt = 0; nt < 4; ++nt) bv[nt] = bias[wcol + 16 * nt + l15];

    float* ob = out + (size_t)b * Tn * On;
    #pragma unroll
    for (int mt = 0; mt < 4; ++mt) {
        #pragma unroll
        for (int i = 0; i < 4; ++i) {
            const int tl = mt * 16 + q * 4 + i;
            const int t  = sIdx[tl];
            const float g = sG[tl];
            float* orow = ob + (size_t)t * On + wcol + l15;
            #pragma unroll
            for (int nt = 0; nt < 4; ++nt)
                atomicAdd(&orow[16 * nt], (acc[mt][nt][i] + bv[nt]) * g);
        }
    }
}

extern "C" void kernel_launch(void* const* d_in, const int* in_sizes, int n_in,
                              void* d_out, int out_size, void* d_ws, size_t ws_size,
                              hipStream_t stream) {
    const float* x    = (const float*)d_in[0];  // (B,E,C,I) fp32
    const int*   idx  = (const int*)  d_in[1];  // (B,E,C) int32
    const float* gate = (const float*)d_in[2];  // (B,E,C) fp32
    const float* w    = (const float*)d_in[3];  // (E,O,I) fp32
    const float* bias = (const float*)d_in[4];  // (O,) fp32
    float* out = (float*)d_out;

    const size_t needY = (size_t)Bn * ECn * On * sizeof(float);  // 67.1 MB

    if (ws_size >= needY) {
        // two-phase: dense GEMM -> y ws, then token-owned gather-combine
        float* yws = (float*)d_ws;
        gemm_y <<<Bn * En * (Cn / TT), 256, 0, stream>>>(x, w, yws);
        combine<<<Bn * (Tn / TT),      256, 0, stream>>>(idx, gate, yws, bias, out);
    } else {
        // fallback: proven atomic-scatter path (round 3)
        uint4* wh4 = (uint4*)d_ws;  // 512 KB packed f16 weights
        prep_w<<<(En * 4 * 4 * On) / 256, 256, 0, stream>>>((const float4*)w, wh4);
        hipMemsetAsync(d_out, 0, (size_t)out_size, stream);
        gemm_scatter<<<Bn * En * (Cn / TT), 256, 0, stream>>>(x, idx, gate, wh4, bias, out);
    }
}

// Round 8
// 124.652 us; speedup vs baseline: 1.3499x; 1.1001x over previous
//
#include <hip/hip_runtime.h>

// Problem constants (fixed by the reference):
constexpr int Bn = 8;     // batch
constexpr int En = 8;     // experts
constexpr int Cn = 1024;  // capacity
constexpr int In = 128;   // in features (K)
constexpr int On = 256;   // out features (N)
constexpr int Tn = 8192;  // num tokens
constexpr int ECn = En * Cn;   // 8192 contributions per batch

constexpr int TT  = 64;   // rows per tile (both kernels)
constexpr int CAP = 16;   // contributors per token (Poisson(1); max over 64K ~10)
constexpr int OVF = 32;   // overflow side-list capacity

typedef __fp16 fp16x2 __attribute__((ext_vector_type(2)));
typedef __fp16 f16x8  __attribute__((ext_vector_type(8)));
typedef float  f32x4  __attribute__((ext_vector_type(4)));

__device__ inline unsigned int pk16(float a, float b) {
    fp16x2 h = __builtin_amdgcn_cvt_pkrtz(a, b);   // RTZ pack (weights/A: proven)
    return __builtin_bit_cast(unsigned int, h);
}
__device__ inline unsigned int pkrtn(float a, float b) {
    fp16x2 h = { (__fp16)a, (__fp16)b };           // v_cvt_f16_f32 = RTN (y store)
    return __builtin_bit_cast(unsigned int, h);
}
__device__ inline f32x4 yconv(uint2 r) {           // decode 4 f16 -> f32
    fp16x2 a = __builtin_bit_cast(fp16x2, r.x);
    fp16x2 b = __builtin_bit_cast(fp16x2, r.y);
    return f32x4{(float)a.x, (float)a.y, (float)b.x, (float)b.y};
}

// ---------------------------------------------------------------------------
// Pack W (E,O,I) f32 -> f16 B-fragment layout (verified round 3):
//   wh4[((e*4+s)*4+q)*256 + col] = W[e][col][32s+8q .. +7]  (8 f16 = uint4)
// ---------------------------------------------------------------------------
__global__ void prep_w(const float4* __restrict__ w4, uint4* __restrict__ wh4) {
    int f = blockIdx.x * 256 + threadIdx.x;  // < E*4*4*256 = 32768
    int col = f & 255, q = (f >> 8) & 3, s = (f >> 10) & 3, e = f >> 12;
    const float4* p = w4 + ((size_t)(e * On + col)) * (In / 4) + (s * 8 + q * 2);
    float4 a = p[0], b = p[1];
    uint4 o;
    o.x = pk16(a.x, a.y); o.y = pk16(a.z, a.w);
    o.z = pk16(b.x, b.y); o.w = pk16(b.z, b.w);
    wh4[f] = o;
}

// ===========================================================================
// PHASE A: dense per-(b,e) GEMM -> y' f16 workspace (permuted layout).
//   y'[row][slab*64 + 4*l15 + nt] = C[row][slab*64 + 16*nt + l15]
//   -> producer stores one contiguous uint2 (4 f16) per row/lane.
//   B-frags from prep'd wh4 (uint4 loads, no VALU convert).
// ===========================================================================
__global__ __launch_bounds__(256, 3)
void gemm_y(const float* __restrict__ x,     // (B,E,C,I) f32
            const uint4* __restrict__ wh4,   // packed f16 W
            __fp16* __restrict__ y)          // (B,E*C,O) f16 ws, permuted cols
{
    __shared__ uint4 Ah[TT * 16];   // 16 KB f16 A tile, frag-swizzled

    const int tid = threadIdx.x;
    const int blk = blockIdx.x;            // (b*8 + e)*16 + ctile
    const int b  = blk >> 7;
    const int e  = (blk >> 4) & 7;
    const int c0 = (blk & 15) * TT;

    const size_t becBase = ((size_t)(b * En + e)) * Cn + c0;
    const float* xrow = x + becBase * In;

    // ---- stage A: 64 consecutive x rows -> f16 frag-swizzled Ah ----
    {
        const int tl = tid >> 2, cq = (tid & 3) * 4;
        const float4* xr = (const float4*)xrow + (size_t)tl * (In / 4);
        #pragma unroll
        for (int it = 0; it < 4; ++it) {
            int cc = cq + it;
            float4 a = xr[2 * cc], b2 = xr[2 * cc + 1];
            uint4 o;
            o.x = pk16(a.x, a.y);   o.y = pk16(a.z, a.w);
            o.z = pk16(b2.x, b2.y); o.w = pk16(b2.z, b2.w);
            Ah[tl * 16 + (cc ^ (tl & 15))] = o;   // verified swizzle
        }
    }

    const int l15  = tid & 15;        // col-in-tile / row-in-tile
    const int q    = (tid >> 4) & 3;  // lane quad
    const int wcol = (tid >> 6) * 64; // wave's 64-column slab

    // ---- B fragments from packed f16 weights (L2-hot, zero VALU) ----
    f16x8 bfr[4][4];
    #pragma unroll
    for (int nt = 0; nt < 4; ++nt)
        #pragma unroll
        for (int s = 0; s < 4; ++s)
            bfr[nt][s] = __builtin_bit_cast(f16x8,
                wh4[(size_t)((e * 4 + s) * 4 + q) * 256 + wcol + 16 * nt + l15]);

    __syncthreads();

    // ---- dense MFMA: 64x256 = A(64x128) * W_e^T(128x256) ----
    f32x4 acc[4][4];
    #pragma unroll
    for (int mt = 0; mt < 4; ++mt)
        #pragma unroll
        for (int nt = 0; nt < 4; ++nt) acc[mt][nt] = f32x4{0.f, 0.f, 0.f, 0.f};

    #pragma unroll
    for (int mt = 0; mt < 4; ++mt) {
        const int tl = mt * 16 + l15;
        f16x8 afr[4];
        #pragma unroll
        for (int s = 0; s < 4; ++s)
            afr[s] = __builtin_bit_cast(f16x8, Ah[tl * 16 + ((4 * s + q) ^ (tl & 15))]);
        #pragma unroll
        for (int nt = 0; nt < 4; ++nt)
            #pragma unroll
            for (int s = 0; s < 4; ++s)
                acc[mt][nt] = __builtin_amdgcn_mfma_f32_16x16x32_f16(
                    afr[s], bfr[nt][s], acc[mt][nt], 0, 0, 0);
    }

    // ---- store y' f16 (RTN): lane stores 4 cols {16nt+l15} as uint2 ----
    __fp16* yb = y + becBase * On;
    #pragma unroll
    for (int mt = 0; mt < 4; ++mt) {
        #pragma unroll
        for (int i = 0; i < 4; ++i) {
            const int tl = mt * 16 + q * 4 + i;
            uint2 o;
            o.x = pkrtn(acc[mt][0][i], acc[mt][1][i]);
            o.y = pkrtn(acc[mt][2][i], acc[mt][3][i]);
            *(uint2*)(yb + (size_t)tl * On + wcol + 4 * l15) = o;
        }
    }
}

// ===========================================================================
// PHASE B: token-owned combine, WAVE-PER-ROW gather (round-6 proven shape).
//   Lane l reads y' halfwords 4l..4l+3 (one uint2) = C-cols
//   cbase+{0,16,32,48} with cbase = (l>>4)*64 + (l&15). Bias/out use the
//   same mapping (4 scalar f32 stores; 16-lane 64B bursts).
// ===========================================================================
__global__ __launch_bounds__(256, 4)
void combine(const int*   __restrict__ idx,   // (B,E,C)
             const float* __restrict__ gate,  // (B,E,C)
             const __fp16* __restrict__ y,    // (B,E*C,O) f16 ws, permuted
             const float* __restrict__ bias,  // (O)
             float* __restrict__ out)         // (B,T,O)
{
    __shared__ int   lcnt[TT];
    __shared__ float gsum[TT];
    __shared__ unsigned short lslot[TT][CAP];
    __shared__ float lgate[TT][CAP];
    __shared__ int ovfCnt;
    __shared__ unsigned ovfE[OVF];
    __shared__ float    ovfG[OVF];

    const int tid = threadIdx.x;
    const int blk = blockIdx.x;           // b*128 + ttile
    const int b  = blk >> 7;
    const int t0 = (blk & 127) * TT;
    const int*   idxb  = idx  + (size_t)b * ECn;
    const float* gateb = gate + (size_t)b * ECn;

    if (tid < TT) { lcnt[tid] = 0; gsum[tid] = 0.f; }
    if (tid == 0) ovfCnt = 0;
    __syncthreads();

    // ---- vectorized scan over this batch's 8192 indices (idx4 + gate4) ----
    {
        const int4*   idx4  = (const int4*)idxb;
        const float4* gate4 = (const float4*)gateb;
        #pragma unroll
        for (int s = 0; s < ECn / 1024; ++s) {     // 8 steps of int4
            int i4 = tid + 256 * s;
            int4   tv = idx4[i4];
            float4 gv = gate4[i4];
            int ec0 = i4 * 4;
            #pragma unroll
            for (int k = 0; k < 4; ++k) {
                int   t = (k == 0) ? tv.x : (k == 1) ? tv.y : (k == 2) ? tv.z : tv.w;
                float g = (k == 0) ? gv.x : (k == 1) ? gv.y : (k == 2) ? gv.z : gv.w;
                unsigned d = (unsigned)(t - t0);
                if (d < (unsigned)TT) {
                    int ec = ec0 + k;
                    atomicAdd(&gsum[d], g);
                    int pos = atomicAdd(&lcnt[d], 1);
                    if (pos < CAP) {
                        lslot[d][pos] = (unsigned short)ec;
                        lgate[d][pos] = g;
                    } else {
                        int o = atomicAdd(&ovfCnt, 1);
                        if (o < OVF) { ovfE[o] = ((unsigned)d << 16) | (unsigned)ec; ovfG[o] = g; }
                    }
                }
            }
        }
    }
    __syncthreads();

    const int wv = tid >> 6;         // wave id 0..3
    const int l  = tid & 63;         // lane: y' halfwords 4l..4l+3
    const int d0 = wv * 16;          // first token owned by this wave
    const __fp16* yb = y + (size_t)b * ECn * On;

    f32x4 acc[16];
    int   n[16];

    // ---- burst: first contributor row of each of the 16 tokens ----
    uint2 raw[16];
    #pragma unroll
    for (int tk = 0; tk < 16; ++tk) {
        n[tk] = min(lcnt[d0 + tk], CAP);
        raw[tk] = uint2{0u, 0u};
        if (n[tk] > 0) {
            const int ec = lslot[d0 + tk][0];
            raw[tk] = *(const uint2*)(yb + (size_t)ec * On + 4 * l);
        }
    }
    #pragma unroll
    for (int tk = 0; tk < 16; ++tk) {
        acc[tk] = f32x4{0.f, 0.f, 0.f, 0.f};
        if (n[tk] > 0) acc[tk] = yconv(raw[tk]) * lgate[d0 + tk][0];
    }

    // ---- remaining contributors (wave-uniform loops; P(n>=2) ~ 26%) ----
    #pragma unroll
    for (int tk = 0; tk < 16; ++tk) {
        for (int j = 1; j < n[tk]; ++j) {
            const int ec = lslot[d0 + tk][j];
            const float g = lgate[d0 + tk][j];
            f32x4 v = yconv(*(const uint2*)(yb + (size_t)ec * On + 4 * l));
            acc[tk] += v * g;
        }
    }

    // ---- rare overflow entries (normally ovfCnt == 0) ----
    const int oc = min(ovfCnt, OVF);
    for (int j = 0; j < oc; ++j) {
        const int dd = (int)(ovfE[j] >> 16);
        const int tk = dd - d0;
        if ((unsigned)tk < 16u) {
            const int ec = (int)(ovfE[j] & 0xFFFFu);
            const float g = ovfG[j];
            f32x4 v = yconv(*(const uint2*)(yb + (size_t)ec * On + 4 * l));
            #pragma unroll
            for (int k = 0; k < 16; ++k)
                if (tk == k) acc[k] += v * g;   // static acc index
        }
    }

    // ---- epilogue: + bias*gsum; cols cbase+{0,16,32,48} ----
    const int cbase = (l >> 4) * 64 + (l & 15);
    const float bv0 = bias[cbase],      bv1 = bias[cbase + 16];
    const float bv2 = bias[cbase + 32], bv3 = bias[cbase + 48];
    #pragma unroll
    for (int tk = 0; tk < 16; ++tk) {
        const int d = d0 + tk;
        const float gs = gsum[d];
        float* orow = out + ((size_t)b * Tn + t0 + d) * On + cbase;
        orow[0]  = acc[tk][0] + bv0 * gs;
        orow[16] = acc[tk][1] + bv1 * gs;
        orow[32] = acc[tk][2] + bv2 * gs;
        orow[48] = acc[tk][3] + bv3 * gs;
    }
}

// ===========================================================================
// FALLBACK (ws too small): proven round-3 path — prep_w + memset + atomic
// scatter GEMM.
// ===========================================================================
__global__ __launch_bounds__(256, 2)
void gemm_scatter(const float* __restrict__ x, const int* __restrict__ idx,
                  const float* __restrict__ gate, const uint4* __restrict__ wh4,
                  const float* __restrict__ bias, float* __restrict__ out)
{
    __shared__ uint4 Ah[TT * 16];
    __shared__ int   sIdx[TT];
    __shared__ float sG[TT];

    const int tid = threadIdx.x;
    const int blk = blockIdx.x;
    const int b  = blk >> 7;
    const int e  = (blk >> 4) & 7;
    const int c0 = (blk & 15) * TT;

    const size_t becBase = ((size_t)(b * En + e)) * Cn + c0;
    const float* xrow = x + becBase * In;

    if (tid < TT) {
        sIdx[tid] = idx[becBase + tid];
        sG[tid]   = gate[becBase + tid];
    }
    {
        const int tl = tid >> 2, cq = (tid & 3) * 4;
        const float4* xr = (const float4*)xrow + (size_t)tl * (In / 4);
        #pragma unroll
        for (int it = 0; it < 4; ++it) {
            int cc = cq + it;
            float4 a = xr[2 * cc], b2 = xr[2 * cc + 1];
            uint4 o;
            o.x = pk16(a.x, a.y);   o.y = pk16(a.z, a.w);
            o.z = pk16(b2.x, b2.y); o.w = pk16(b2.z, b2.w);
            Ah[tl * 16 + (cc ^ (tl & 15))] = o;
        }
    }
    const int l15  = tid & 15;
    const int q    = (tid >> 4) & 3;
    const int wcol = (tid >> 6) * 64;

    f16x8 bfr[4][4];
    #pragma unroll
    for (int nt = 0; nt < 4; ++nt)
        #pragma unroll
        for (int s = 0; s < 4; ++s)
            bfr[nt][s] = __builtin_bit_cast(f16x8,
                wh4[(size_t)((e * 4 + s) * 4 + q) * 256 + wcol + 16 * nt + l15]);

    __syncthreads();

    f32x4 acc[4][4];
    #pragma unroll
    for (int mt = 0; mt < 4; ++mt)
        #pragma unroll
        for (int nt = 0; nt < 4; ++nt) acc[mt][nt] = f32x4{0.f, 0.f, 0.f, 0.f};

    #pragma unroll
    for (int mt = 0; mt < 4; ++mt) {
        const int tl = mt * 16 + l15;
        f16x8 afr[4];
        #pragma unroll
        for (int s = 0; s < 4; ++s)
            afr[s] = __builtin_bit_cast(f16x8, Ah[tl * 16 + ((4 * s + q) ^ (tl & 15))]);
        #pragma unroll
        for (int nt = 0; nt < 4; ++nt)
            #pragma unroll
            for (int s = 0; s < 4; ++s)
                acc[mt][nt] = __builtin_amdgcn_mfma_f32_16x16x32_f16(
                    afr[s], bfr[nt][s], acc[mt][nt], 0, 0, 0);
    }

    float bv[4];
    #pragma unroll
    for (int nt = 0; nt < 4; ++nt) bv[nt] = bias[wcol + 16 * nt + l15];

    float* ob = out + (size_t)b * Tn * On;
    #pragma unroll
    for (int mt = 0; mt < 4; ++mt) {
        #pragma unroll
        for (int i = 0; i < 4; ++i) {
            const int tl = mt * 16 + q * 4 + i;
            const int t  = sIdx[tl];
            const float g = sG[tl];
            float* orow = ob + (size_t)t * On + wcol + l15;
            #pragma unroll
            for (int nt = 0; nt < 4; ++nt)
                atomicAdd(&orow[16 * nt], (acc[mt][nt][i] + bv[nt]) * g);
        }
    }
}

extern "C" void kernel_launch(void* const* d_in, const int* in_sizes, int n_in,
                              void* d_out, int out_size, void* d_ws, size_t ws_size,
                              hipStream_t stream) {
    const float* x    = (const float*)d_in[0];  // (B,E,C,I) fp32
    const int*   idx  = (const int*)  d_in[1];  // (B,E,C) int32
    const float* gate = (const float*)d_in[2];  // (B,E,C) fp32
    const float* w    = (const float*)d_in[3];  // (E,O,I) fp32
    const float* bias = (const float*)d_in[4];  // (O,) fp32
    float* out = (float*)d_out;

    const size_t whBytes = 1u << 20;                              // 1 MB slot (512 KB used)
    const size_t needWs  = whBytes + (size_t)Bn * ECn * On * 2;   // + 33.6 MB f16 y

    uint4* wh4 = (uint4*)d_ws;
    prep_w<<<(En * 4 * 4 * On) / 256, 256, 0, stream>>>((const float4*)w, wh4);

    if (ws_size >= needWs) {
        // two-phase: dense GEMM -> f16 y' ws, then token-owned gather-combine
        __fp16* yws = (__fp16*)((char*)d_ws + whBytes);
        gemm_y <<<Bn * En * (Cn / TT), 256, 0, stream>>>(x, wh4, yws);
        combine<<<Bn * (Tn / TT),      256, 0, stream>>>(idx, gate, yws, bias, out);
    } else {
        // fallback: proven atomic-scatter path (round 3)
        hipMemsetAsync(d_out, 0, (size_t)out_size, stream);
        gemm_scatter<<<Bn * En * (Cn / TT), 256, 0, stream>>>(x, idx, gate, wh4, bias, out);
    }
}

// Round 9
// 123.137 us; speedup vs baseline: 1.3665x; 1.0123x over previous
//
#include <hip/hip_runtime.h>

// Problem constants (fixed by the reference):
constexpr int Bn = 8;     // batch
constexpr int En = 8;     // experts
constexpr int Cn = 1024;  // capacity
constexpr int In = 128;   // in features (K)
constexpr int On = 256;   // out features (N)
constexpr int Tn = 8192;  // num tokens
constexpr int ECn = En * Cn;   // 8192 contributions per batch

constexpr int TT  = 64;   // capacity rows per gemm tile
constexpr int TTC = 128;  // tokens per combine block (512 threads)
constexpr int CAP = 16;   // contributors per token (Poisson(1); max over 64K ~10)
constexpr int OVF = 32;   // overflow side-list capacity

typedef __fp16 fp16x2 __attribute__((ext_vector_type(2)));
typedef __fp16 f16x8  __attribute__((ext_vector_type(8)));
typedef float  f32x4  __attribute__((ext_vector_type(4)));

__device__ inline unsigned int pk16(float a, float b) {
    fp16x2 h = __builtin_amdgcn_cvt_pkrtz(a, b);   // RTZ pack (weights/A: proven)
    return __builtin_bit_cast(unsigned int, h);
}
__device__ inline unsigned int pkrtn(float a, float b) {
    fp16x2 h = { (__fp16)a, (__fp16)b };           // v_cvt_f16_f32 = RTN (y store)
    return __builtin_bit_cast(unsigned int, h);
}
__device__ inline f32x4 yconv(uint2 r) {           // decode 4 f16 -> f32
    fp16x2 a = __builtin_bit_cast(fp16x2, r.x);
    fp16x2 b = __builtin_bit_cast(fp16x2, r.y);
    return f32x4{(float)a.x, (float)a.y, (float)b.x, (float)b.y};
}

// ---------------------------------------------------------------------------
// Pack W (E,O,I) f32 -> f16 B-fragment layout (verified round 3):
//   wh4[((e*4+s)*4+q)*256 + col] = W[e][col][32s+8q .. +7]  (8 f16 = uint4)
// ---------------------------------------------------------------------------
__global__ void prep_w(const float4* __restrict__ w4, uint4* __restrict__ wh4) {
    int f = blockIdx.x * 256 + threadIdx.x;  // < E*4*4*256 = 32768
    int col = f & 255, q = (f >> 8) & 3, s = (f >> 10) & 3, e = f >> 12;
    const float4* p = w4 + ((size_t)(e * On + col)) * (In / 4) + (s * 8 + q * 2);
    float4 a = p[0], b = p[1];
    uint4 o;
    o.x = pk16(a.x, a.y); o.y = pk16(a.z, a.w);
    o.z = pk16(b.x, b.y); o.w = pk16(b.z, b.w);
    wh4[f] = o;
}

// ===========================================================================
// PHASE A: dense per-(b,e) GEMM -> y' f16 workspace (permuted layout).
//   y'[row][slab*64 + 4*l15 + nt] = C[row][slab*64 + 16*nt + l15]
//   -> producer stores one contiguous uint2 (4 f16) per row/lane.
//   (unchanged from round 8 — proven)
// ===========================================================================
__global__ __launch_bounds__(256, 3)
void gemm_y(const float* __restrict__ x,     // (B,E,C,I) f32
            const uint4* __restrict__ wh4,   // packed f16 W
            __fp16* __restrict__ y)          // (B,E*C,O) f16 ws, permuted cols
{
    __shared__ uint4 Ah[TT * 16];   // 16 KB f16 A tile, frag-swizzled

    const int tid = threadIdx.x;
    const int blk = blockIdx.x;            // (b*8 + e)*16 + ctile
    const int b  = blk >> 7;
    const int e  = (blk >> 4) & 7;
    const int c0 = (blk & 15) * TT;

    const size_t becBase = ((size_t)(b * En + e)) * Cn + c0;
    const float* xrow = x + becBase * In;

    // ---- stage A: 64 consecutive x rows -> f16 frag-swizzled Ah ----
    {
        const int tl = tid >> 2, cq = (tid & 3) * 4;
        const float4* xr = (const float4*)xrow + (size_t)tl * (In / 4);
        #pragma unroll
        for (int it = 0; it < 4; ++it) {
            int cc = cq + it;
            float4 a = xr[2 * cc], b2 = xr[2 * cc + 1];
            uint4 o;
            o.x = pk16(a.x, a.y);   o.y = pk16(a.z, a.w);
            o.z = pk16(b2.x, b2.y); o.w = pk16(b2.z, b2.w);
            Ah[tl * 16 + (cc ^ (tl & 15))] = o;   // verified swizzle
        }
    }

    const int l15  = tid & 15;        // col-in-tile / row-in-tile
    const int q    = (tid >> 4) & 3;  // lane quad
    const int wcol = (tid >> 6) * 64; // wave's 64-column slab

    // ---- B fragments from packed f16 weights (L2-hot, zero VALU) ----
    f16x8 bfr[4][4];
    #pragma unroll
    for (int nt = 0; nt < 4; ++nt)
        #pragma unroll
        for (int s = 0; s < 4; ++s)
            bfr[nt][s] = __builtin_bit_cast(f16x8,
                wh4[(size_t)((e * 4 + s) * 4 + q) * 256 + wcol + 16 * nt + l15]);

    __syncthreads();

    // ---- dense MFMA: 64x256 = A(64x128) * W_e^T(128x256) ----
    f32x4 acc[4][4];
    #pragma unroll
    for (int mt = 0; mt < 4; ++mt)
        #pragma unroll
        for (int nt = 0; nt < 4; ++nt) acc[mt][nt] = f32x4{0.f, 0.f, 0.f, 0.f};

    #pragma unroll
    for (int mt = 0; mt < 4; ++mt) {
        const int tl = mt * 16 + l15;
        f16x8 afr[4];
        #pragma unroll
        for (int s = 0; s < 4; ++s)
            afr[s] = __builtin_bit_cast(f16x8, Ah[tl * 16 + ((4 * s + q) ^ (tl & 15))]);
        #pragma unroll
        for (int nt = 0; nt < 4; ++nt)
            #pragma unroll
            for (int s = 0; s < 4; ++s)
                acc[mt][nt] = __builtin_amdgcn_mfma_f32_16x16x32_f16(
                    afr[s], bfr[nt][s], acc[mt][nt], 0, 0, 0);
    }

    // ---- store y' f16 (RTN): lane stores 4 cols {16nt+l15} as uint2 ----
    __fp16* yb = y + becBase * On;
    #pragma unroll
    for (int mt = 0; mt < 4; ++mt) {
        #pragma unroll
        for (int i = 0; i < 4; ++i) {
            const int tl = mt * 16 + q * 4 + i;
            uint2 o;
            o.x = pkrtn(acc[mt][0][i], acc[mt][1][i]);
            o.y = pkrtn(acc[mt][2][i], acc[mt][3][i]);
            *(uint2*)(yb + (size_t)tl * On + wcol + 4 * l15) = o;
        }
    }
}

// ===========================================================================
// PHASE B: token-owned combine, WAVE-PER-ROW gather.
//   512 threads / block, TTC=128 tokens -> 512 blocks total: halves the
//   aggregate redundant idx/gate scan vs TT=64 (4 int4 steps per thread).
//   8 waves x 16 tokens each; per-wave gather shape identical to round 8.
// ===========================================================================
__global__ __launch_bounds__(512, 2)
void combine(const int*   __restrict__ idx,   // (B,E,C)
             const float* __restrict__ gate,  // (B,E,C)
             const __fp16* __restrict__ y,    // (B,E*C,O) f16 ws, permuted
             const float* __restrict__ bias,  // (O)
             float* __restrict__ out)         // (B,T,O)
{
    __shared__ int   lcnt[TTC];
    __shared__ float gsum[TTC];
    __shared__ unsigned short lslot[TTC][CAP];
    __shared__ float lgate[TTC][CAP];
    __shared__ int ovfCnt;
    __shared__ unsigned ovfE[OVF];
    __shared__ float    ovfG[OVF];

    const int tid = threadIdx.x;
    const int blk = blockIdx.x;           // b*64 + ttile
    const int b  = blk >> 6;
    const int t0 = (blk & 63) * TTC;
    const int*   idxb  = idx  + (size_t)b * ECn;
    const float* gateb = gate + (size_t)b * ECn;

    if (tid < TTC) { lcnt[tid] = 0; gsum[tid] = 0.f; }
    if (tid == 0) ovfCnt = 0;
    __syncthreads();

    // ---- vectorized scan over this batch's 8192 indices (idx4 + gate4) ----
    {
        const int4*   idx4  = (const int4*)idxb;
        const float4* gate4 = (const float4*)gateb;
        #pragma unroll
        for (int s = 0; s < ECn / (4 * 512); ++s) {   // 4 steps of int4
            int i4 = tid + 512 * s;
            int4   tv = idx4[i4];
            float4 gv = gate4[i4];
            int ec0 = i4 * 4;
            #pragma unroll
            for (int k = 0; k < 4; ++k) {
                int   t = (k == 0) ? tv.x : (k == 1) ? tv.y : (k == 2) ? tv.z : tv.w;
                float g = (k == 0) ? gv.x : (k == 1) ? gv.y : (k == 2) ? gv.z : gv.w;
                unsigned d = (unsigned)(t - t0);
                if (d < (unsigned)TTC) {
                    int ec = ec0 + k;
                    atomicAdd(&gsum[d], g);
                    int pos = atomicAdd(&lcnt[d], 1);
                    if (pos < CAP) {
                        lslot[d][pos] = (unsigned short)ec;
                        lgate[d][pos] = g;
                    } else {
                        int o = atomicAdd(&ovfCnt, 1);
                        if (o < OVF) { ovfE[o] = ((unsigned)d << 16) | (unsigned)ec; ovfG[o] = g; }
                    }
                }
            }
        }
    }
    __syncthreads();

    const int wv = tid >> 6;         // wave id 0..7
    const int l  = tid & 63;         // lane: y' halfwords 4l..4l+3
    const int d0 = wv * 16;          // first token owned by this wave
    const __fp16* yb = y + (size_t)b * ECn * On;

    f32x4 acc[16];
    int   n[16];

    // ---- burst: first contributor row of each of the 16 tokens ----
    uint2 raw[16];
    #pragma unroll
    for (int tk = 0; tk < 16; ++tk) {
        n[tk] = min(lcnt[d0 + tk], CAP);
        raw[tk] = uint2{0u, 0u};
        if (n[tk] > 0) {
            const int ec = lslot[d0 + tk][0];
            raw[tk] = *(const uint2*)(yb + (size_t)ec * On + 4 * l);
        }
    }
    #pragma unroll
    for (int tk = 0; tk < 16; ++tk) {
        acc[tk] = f32x4{0.f, 0.f, 0.f, 0.f};
        if (n[tk] > 0) acc[tk] = yconv(raw[tk]) * lgate[d0 + tk][0];
    }

    // ---- remaining contributors (wave-uniform loops; P(n>=2) ~ 26%) ----
    #pragma unroll
    for (int tk = 0; tk < 16; ++tk) {
        for (int j = 1; j < n[tk]; ++j) {
            const int ec = lslot[d0 + tk][j];
            const float g = lgate[d0 + tk][j];
            f32x4 v = yconv(*(const uint2*)(yb + (size_t)ec * On + 4 * l));
            acc[tk] += v * g;
        }
    }

    // ---- rare overflow entries (normally ovfCnt == 0) ----
    const int oc = min(ovfCnt, OVF);
    for (int j = 0; j < oc; ++j) {
        const int dd = (int)(ovfE[j] >> 16);
        const int tk = dd - d0;
        if ((unsigned)tk < 16u) {
            const int ec = (int)(ovfE[j] & 0xFFFFu);
            const float g = ovfG[j];
            f32x4 v = yconv(*(const uint2*)(yb + (size_t)ec * On + 4 * l));
            #pragma unroll
            for (int k = 0; k < 16; ++k)
                if (tk == k) acc[k] += v * g;   // static acc index
        }
    }

    // ---- epilogue: + bias*gsum; cols cbase+{0,16,32,48} ----
    const int cbase = (l >> 4) * 64 + (l & 15);
    const float bv0 = bias[cbase],      bv1 = bias[cbase + 16];
    const float bv2 = bias[cbase + 32], bv3 = bias[cbase + 48];
    #pragma unroll
    for (int tk = 0; tk < 16; ++tk) {
        const int d = d0 + tk;
        const float gs = gsum[d];
        float* orow = out + ((size_t)b * Tn + t0 + d) * On + cbase;
        orow[0]  = acc[tk][0] + bv0 * gs;
        orow[16] = acc[tk][1] + bv1 * gs;
        orow[32] = acc[tk][2] + bv2 * gs;
        orow[48] = acc[tk][3] + bv3 * gs;
    }
}

// ===========================================================================
// FALLBACK (ws too small): proven round-3 path — prep_w + memset + atomic
// scatter GEMM.
// ===========================================================================
__global__ __launch_bounds__(256, 2)
void gemm_scatter(const float* __restrict__ x, const int* __restrict__ idx,
                  const float* __restrict__ gate, const uint4* __restrict__ wh4,
                  const float* __restrict__ bias, float* __restrict__ out)
{
    __shared__ uint4 Ah[TT * 16];
    __shared__ int   sIdx[TT];
    __shared__ float sG[TT];

    const int tid = threadIdx.x;
    const int blk = blockIdx.x;
    const int b  = blk >> 7;
    const int e  = (blk >> 4) & 7;
    const int c0 = (blk & 15) * TT;

    const size_t becBase = ((size_t)(b * En + e)) * Cn + c0;
    const float* xrow = x + becBase * In;

    if (tid < TT) {
        sIdx[tid] = idx[becBase + tid];
        sG[tid]   = gate[becBase + tid];
    }
    {
        const int tl = tid >> 2, cq = (tid & 3) * 4;
        const float4* xr = (const float4*)xrow + (size_t)tl * (In / 4);
        #pragma unroll
        for (int it = 0; it < 4; ++it) {
            int cc = cq + it;
            float4 a = xr[2 * cc], b2 = xr[2 * cc + 1];
            uint4 o;
            o.x = pk16(a.x, a.y);   o.y = pk16(a.z, a.w);
            o.z = pk16(b2.x, b2.y); o.w = pk16(b2.z, b2.w);
            Ah[tl * 16 + (cc ^ (tl & 15))] = o;
        }
    }
    const int l15  = tid & 15;
    const int q    = (tid >> 4) & 3;
    const int wcol = (tid >> 6) * 64;

    f16x8 bfr[4][4];
    #pragma unroll
    for (int nt = 0; nt < 4; ++nt)
        #pragma unroll
        for (int s = 0; s < 4; ++s)
            bfr[nt][s] = __builtin_bit_cast(f16x8,
                wh4[(size_t)((e * 4 + s) * 4 + q) * 256 + wcol + 16 * nt + l15]);

    __syncthreads();

    f32x4 acc[4][4];
    #pragma unroll
    for (int mt = 0; mt < 4; ++mt)
        #pragma unroll
        for (int nt = 0; nt < 4; ++nt) acc[mt][nt] = f32x4{0.f, 0.f, 0.f, 0.f};

    #pragma unroll
    for (int mt = 0; mt < 4; ++mt) {
        const int tl = mt * 16 + l15;
        f16x8 afr[4];
        #pragma unroll
        for (int s = 0; s < 4; ++s)
            afr[s] = __builtin_bit_cast(f16x8, Ah[tl * 16 + ((4 * s + q) ^ (tl & 15))]);
        #pragma unroll
        for (int nt = 0; nt < 4; ++nt)
            #pragma unroll
            for (int s = 0; s < 4; ++s)
                acc[mt][nt] = __builtin_amdgcn_mfma_f32_16x16x32_f16(
                    afr[s], bfr[nt][s], acc[mt][nt], 0, 0, 0);
    }

    float bv[4];
    #pragma unroll
    for (int nt = 0; nt < 4; ++nt) bv[nt] = bias[wcol + 16 * nt + l15];

    float* ob = out + (size_t)b * Tn * On;
    #pragma unroll
    for (int mt = 0; mt < 4; ++mt) {
        #pragma unroll
        for (int i = 0; i < 4; ++i) {
            const int tl = mt * 16 + q * 4 + i;
            const int t  = sIdx[tl];
            const float g = sG[tl];
            float* orow = ob + (size_t)t * On + wcol + l15;
            #pragma unroll
            for (int nt = 0; nt < 4; ++nt)
                atomicAdd(&orow[16 * nt], (acc[mt][nt][i] + bv[nt]) * g);
        }
    }
}

extern "C" void kernel_launch(void* const* d_in, const int* in_sizes, int n_in,
                              void* d_out, int out_size, void* d_ws, size_t ws_size,
                              hipStream_t stream) {
    const float* x    = (const float*)d_in[0];  // (B,E,C,I) fp32
    const int*   idx  = (const int*)  d_in[1];  // (B,E,C) int32
    const float* gate = (const float*)d_in[2];  // (B,E,C) fp32
    const float* w    = (const float*)d_in[3];  // (E,O,I) fp32
    const float* bias = (const float*)d_in[4];  // (O,) fp32
    float* out = (float*)d_out;

    const size_t whBytes = 1u << 20;                              // 1 MB slot (512 KB used)
    const size_t needWs  = whBytes + (size_t)Bn * ECn * On * 2;   // + 33.6 MB f16 y

    uint4* wh4 = (uint4*)d_ws;
    prep_w<<<(En * 4 * 4 * On) / 256, 256, 0, stream>>>((const float4*)w, wh4);

    if (ws_size >= needWs) {
        // two-phase: dense GEMM -> f16 y' ws, then token-owned gather-combine
        __fp16* yws = (__fp16*)((char*)d_ws + whBytes);
        gemm_y <<<Bn * En * (Cn / TT), 256, 0, stream>>>(x, wh4, yws);
        combine<<<Bn * (Tn / TTC),     512, 0, stream>>>(idx, gate, yws, bias, out);
    } else {
        // fallback: proven atomic-scatter path (round 3)
        hipMemsetAsync(d_out, 0, (size_t)out_size, stream);
        gemm_scatter<<<Bn * En * (Cn / TT), 256, 0, stream>>>(x, idx, gate, wh4, bias, out);
    }
}